// Round 1
// baseline (10.401 us; speedup 1.0000x reference)
//
#include <hip/hip_runtime.h>
#include <hip/hip_bf16.h>

// Cross-entropy loss: out = -mean_i log(pred[i, label[i]])
// pred: [B, C] float32, label: [B] int32 (JAX int64 downcast), out: scalar f32.
// Only B gathered elements of pred are needed -> tiny latency-bound kernel.

__global__ __launch_bounds__(1024)
void ce_gather_log_mean(const float* __restrict__ pred,
                        const int* __restrict__ label,
                        float* __restrict__ out,
                        int B, long long C) {
    const int tid = threadIdx.x;
    float acc = 0.0f;

    // Grid is a single block of 1024 threads; each thread covers B/1024 rows.
    // Loop kept simple; per-iteration label load is coalesced, pred load is
    // an independent scattered load -> compiler pipelines them (8-deep MLP).
    #pragma unroll 8
    for (int i = tid; i < B; i += 1024) {
        int lbl = label[i];
        float p = pred[(long long)i * C + (long long)lbl];
        acc += logf(p);
    }

    // Wave (64-lane) butterfly reduction.
    #pragma unroll
    for (int off = 32; off > 0; off >>= 1)
        acc += __shfl_down(acc, off, 64);

    __shared__ float s_partial[16];
    const int wave = tid >> 6;
    const int lane = tid & 63;
    if (lane == 0) s_partial[wave] = acc;
    __syncthreads();

    if (tid == 0) {
        float total = 0.0f;
        #pragma unroll
        for (int w = 0; w < 16; ++w) total += s_partial[w];
        out[0] = -total / (float)B;
    }
}

extern "C" void kernel_launch(void* const* d_in, const int* in_sizes, int n_in,
                              void* d_out, int out_size, void* d_ws, size_t ws_size,
                              hipStream_t stream) {
    const float* pred  = (const float*)d_in[0];
    const int*   label = (const int*)d_in[1];
    float*       out   = (float*)d_out;

    const int B = in_sizes[1];
    const long long C = (long long)in_sizes[0] / (long long)B;

    ce_gather_log_mean<<<1, 1024, 0, stream>>>(pred, label, out, B, C);
}